// Round 5
// baseline (1440.190 us; speedup 1.0000x reference)
//
#include <hip/hip_runtime.h>
#include <stdint.h>

#define IN_CH 11
#define EDGE_CH 22
#define HID 64
#define N_CLS 2
#define N_GRAPHS 256

// Coarse buckets: 256 nodes per bucket (node >> 8). N=100000 -> 391 buckets.
#define BK_SHIFT 8
#define BK_NODES 256
#define MAXBUK 512          // padded power-of-2 for scans
#define L1_CHUNK 4096       // edges per binscatter block
#define L2_CAP 16384        // LDS staging entries in bucket_csr (64 KB)

// src-side pack: (local<<22)|edge_id   (edge_id < 2^22 = 4.19M)
// dst-side pack: (local<<17)|src_id    (src_id  < 2^17 = 131072)
#define SRC_SHIFT 22
#define DST_SHIFT 17

// ---------------------------------------------------------------------------
// Step 1: coarse bucket histogram (LDS-staged, one flush per block)
// ---------------------------------------------------------------------------
__global__ void prehist_kernel(const int* __restrict__ src, const int* __restrict__ dst,
                               int* __restrict__ bc_src, int* __restrict__ bc_dst,
                               int E, int nbuk) {
    __shared__ int h_s[MAXBUK], h_d[MAXBUK];
    int t = threadIdx.x;  // 256
    for (int i = t; i < MAXBUK; i += 256) { h_s[i] = 0; h_d[i] = 0; }
    __syncthreads();
    int per = (E + gridDim.x - 1) / gridDim.x;
    int lo = blockIdx.x * per, hi = min(E, lo + per);
    for (int i = lo + t; i < hi; i += 256) {
        atomicAdd(&h_s[src[i] >> BK_SHIFT], 1);
        atomicAdd(&h_d[dst[i] >> BK_SHIFT], 1);
    }
    __syncthreads();
    for (int i = t; i < nbuk; i += 256) {
        if (h_s[i]) atomicAdd(&bc_src[i], h_s[i]);
        if (h_d[i]) atomicAdd(&bc_dst[i], h_d[i]);
    }
}

// ---------------------------------------------------------------------------
// Step 2: scan bucket counts -> bucket base offsets (+ cursor copies).
// ---------------------------------------------------------------------------
__global__ void bucket_scan_kernel(const int* __restrict__ bc_src, const int* __restrict__ bc_dst,
                                   int* __restrict__ boff_src, int* __restrict__ boff_dst,
                                   int* __restrict__ gcur_src, int* __restrict__ gcur_dst,
                                   int* __restrict__ off_dst,
                                   int nbuk, int N, int E) {
    __shared__ int a[MAXBUK], b[MAXBUK];
    int t = threadIdx.x;  // 512
    int ca = (t < nbuk) ? bc_src[t] : 0;
    int cb = (t < nbuk) ? bc_dst[t] : 0;
    a[t] = ca; b[t] = cb;
    __syncthreads();
    for (int d = 1; d < MAXBUK; d <<= 1) {
        int ua = (t >= d) ? a[t - d] : 0;
        int ub = (t >= d) ? b[t - d] : 0;
        __syncthreads();
        a[t] += ua; b[t] += ub;
        __syncthreads();
    }
    if (t < nbuk) {
        int ea = a[t] - ca, eb = b[t] - cb;
        boff_src[t] = ea; gcur_src[t] = ea;
        boff_dst[t] = eb; gcur_dst[t] = eb;
    }
    if (t == 0) {
        boff_src[nbuk] = E; boff_dst[nbuk] = E;
        off_dst[N] = E;
    }
}

// ---------------------------------------------------------------------------
// Step 3: bin edges by coarse bucket, LDS-sorted per 4096-edge chunk.
// ---------------------------------------------------------------------------
__global__ void binscatter_kernel(const int* __restrict__ src, const int* __restrict__ dst,
                                  int* __restrict__ gcur_src, int* __restrict__ gcur_dst,
                                  uint32_t* __restrict__ bin_src, uint32_t* __restrict__ bin_dst,
                                  int E, int nbuk) {
    __shared__ int h_s[MAXBUK], h_d[MAXBUK];
    __shared__ int off_s[MAXBUK], off_d[MAXBUK];
    __shared__ int cur_s[MAXBUK], cur_d[MAXBUK];
    __shared__ int base_s[MAXBUK], base_d[MAXBUK];
    __shared__ uint32_t st_s[L1_CHUNK], st_d[L1_CHUNK];
    __shared__ unsigned short bk_s[L1_CHUNK], bk_d[L1_CHUNK];

    int t = threadIdx.x;  // 512
    int e0 = blockIdx.x * L1_CHUNK;
    int ecnt = min(E - e0, L1_CHUNK);

    h_s[t] = 0; h_d[t] = 0;
    __syncthreads();
    for (int i = t; i < ecnt; i += 512) {
        atomicAdd(&h_s[src[e0 + i] >> BK_SHIFT], 1);
        atomicAdd(&h_d[dst[e0 + i] >> BK_SHIFT], 1);
    }
    __syncthreads();
    int cs = h_s[t], cd = h_d[t];
    for (int d = 1; d < MAXBUK; d <<= 1) {
        int us = (t >= d) ? h_s[t - d] : 0;
        int ud = (t >= d) ? h_d[t - d] : 0;
        __syncthreads();
        h_s[t] += us; h_d[t] += ud;
        __syncthreads();
    }
    int ex_s = h_s[t] - cs, ex_d = h_d[t] - cd;
    off_s[t] = ex_s; cur_s[t] = ex_s;
    off_d[t] = ex_d; cur_d[t] = ex_d;
    if (cs > 0) base_s[t] = atomicAdd(&gcur_src[t], cs);
    if (cd > 0) base_d[t] = atomicAdd(&gcur_dst[t], cd);
    __syncthreads();
    for (int i = t; i < ecnt; i += 512) {
        int e = e0 + i;
        int s = src[e], d = dst[e];
        int bs = s >> BK_SHIFT, bd = d >> BK_SHIFT;
        int ps = atomicAdd(&cur_s[bs], 1);
        st_s[ps] = ((uint32_t)(s & (BK_NODES - 1)) << SRC_SHIFT) | (uint32_t)e;
        bk_s[ps] = (unsigned short)bs;
        int pd = atomicAdd(&cur_d[bd], 1);
        st_d[pd] = ((uint32_t)(d & (BK_NODES - 1)) << DST_SHIFT) | (uint32_t)s;
        bk_d[pd] = (unsigned short)bd;
    }
    __syncthreads();
    for (int i = t; i < ecnt; i += 512) {
        int b1 = bk_s[i];
        bin_src[base_s[b1] + i - off_s[b1]] = st_s[i];
        int b2 = bk_d[i];
        bin_dst[base_d[b2] + i - off_d[b2]] = st_d[i];
    }
}

// ---------------------------------------------------------------------------
// Step 4 (dst only): per-bucket fine counting sort -> dst-CSR, LDS-staged.
// ---------------------------------------------------------------------------
__global__ void bucket_csr_kernel(const uint32_t* __restrict__ bin_dst,
                                  const int* __restrict__ boff_dst,
                                  int* __restrict__ dst_srcid, int* __restrict__ off_dst,
                                  int nbuk, int N) {
    int b = blockIdx.x;
    __shared__ int hist[BK_NODES];
    __shared__ int cursor[BK_NODES];
    __shared__ uint32_t stage[L2_CAP];

    int t = threadIdx.x;  // 256
    int base = boff_dst[b];
    int cnt = boff_dst[b + 1] - base;
    int n0 = b << BK_SHIFT;
    int NL = min(N - n0, BK_NODES);
    uint32_t mask = (1u << DST_SHIFT) - 1;

    hist[t] = 0;
    __syncthreads();
    for (int i = t; i < cnt; i += 256) {
        atomicAdd(&hist[bin_dst[base + i] >> DST_SHIFT], 1);
    }
    __syncthreads();
    int c = hist[t];
    for (int d = 1; d < BK_NODES; d <<= 1) {
        int u = (t >= d) ? hist[t - d] : 0;
        __syncthreads();
        hist[t] += u;
        __syncthreads();
    }
    int excl = hist[t] - c;
    cursor[t] = excl;
    if (t < NL) off_dst[n0 + t] = base + excl;
    __syncthreads();
    for (int i = t; i < cnt; i += 256) {
        uint32_t w = bin_dst[base + i];
        int local = (int)(w >> DST_SHIFT);
        int pos = atomicAdd(&cursor[local], 1);
        uint32_t payload = w & mask;
        if (pos < L2_CAP) stage[pos] = payload;
        else dst_srcid[base + pos] = (int)payload;   // rare overflow path
    }
    __syncthreads();
    int lim = min(cnt, L2_CAP);
    for (int i = t; i < lim; i += 256) dst_srcid[base + i] = (int)stage[i];
}

// ---------------------------------------------------------------------------
// bucket_ea: per coarse bucket, accumulate edge_attr rows into LDS by src
// local id (LDS float atomics), count outdeg, then emit
//   x0[n] = x[n] + s_ea[n]@we.T + outdeg(n)*be
// Replaces bucket_csr(src half) + ea_gather + x0_update.
// ---------------------------------------------------------------------------
__global__ void bucket_ea_kernel(const uint32_t* __restrict__ bin_src,
                                 const int* __restrict__ boff_src,
                                 const float* __restrict__ ea,
                                 const float* __restrict__ x,
                                 const float* __restrict__ we,
                                 const float* __restrict__ be,
                                 float* __restrict__ x0,
                                 int nbuk, int N) {
    __shared__ float s_ea[BK_NODES][EDGE_CH];   // 22.5 KB
    __shared__ int s_cnt[BK_NODES];
    __shared__ float s_we[IN_CH * EDGE_CH];
    __shared__ float s_be[IN_CH];
    int t = threadIdx.x;  // 256
    int b = blockIdx.x;
    int base = boff_src[b];
    int cnt = boff_src[b + 1] - base;
    int n0 = b << BK_SHIFT;
    int NL = min(N - n0, BK_NODES);

    for (int i = t; i < IN_CH * EDGE_CH; i += 256) s_we[i] = we[i];
    if (t < IN_CH) s_be[t] = be[t];
    s_cnt[t] = 0;
#pragma unroll
    for (int c = 0; c < EDGE_CH; ++c) s_ea[t][c] = 0.0f;
    __syncthreads();

    const float2* ea2 = (const float2*)ea;
    const uint32_t emask = (1u << SRC_SHIFT) - 1;
    for (int i = t; i < cnt; i += 256) {
        uint32_t w = bin_src[base + i];
        int local = (int)(w >> SRC_SHIFT);
        long eid = (long)(w & emask);
        atomicAdd(&s_cnt[local], 1);
        const float2* row = ea2 + eid * (EDGE_CH / 2);
        float2 v[EDGE_CH / 2];
#pragma unroll
        for (int c = 0; c < EDGE_CH / 2; ++c) v[c] = row[c];   // 11 loads in flight
#pragma unroll
        for (int c = 0; c < EDGE_CH / 2; ++c) {
            atomicAdd(&s_ea[local][2 * c], v[c].x);
            atomicAdd(&s_ea[local][2 * c + 1], v[c].y);
        }
    }
    __syncthreads();

    if (t < NL) {
        int n = n0 + t;
        float cntf = (float)s_cnt[t];
        float a[EDGE_CH];
#pragma unroll
        for (int c = 0; c < EDGE_CH; ++c) a[c] = s_ea[t][c];
#pragma unroll
        for (int o = 0; o < IN_CH; ++o) {
            float acc = x[(long)n * IN_CH + o] + cntf * s_be[o];
#pragma unroll
            for (int c = 0; c < EDGE_CH; ++c) acc += a[c] * s_we[o * EDGE_CH + c];
            x0[(long)n * IN_CH + o] = acc;
        }
    }
}

// ---------------------------------------------------------------------------
// layer1_fused: mean-agg over x0 (11 ch) + relu(mean@l1w.T + l1b + x0@r1w.T)
// Wave per node; 4 groups of 16 lanes, 4-deep unroll (16 rows in flight).
// Persistent grid; weights staged once per block.
// ---------------------------------------------------------------------------
__global__ void layer1_fused(const float* __restrict__ x0,
                             const int* __restrict__ off_dst,
                             const int* __restrict__ srcid,
                             const float* __restrict__ lw,
                             const float* __restrict__ lb,
                             const float* __restrict__ rw,
                             float* __restrict__ h_out, int N) {
    __shared__ float s_lw[IN_CH][HID];
    __shared__ float s_rw[IN_CH][HID];
    __shared__ float s_lb[HID];
    __shared__ float s_mean[4][IN_CH];
    __shared__ float s_hin[4][IN_CH];
    for (int i = threadIdx.x; i < HID * IN_CH; i += 256) {
        int o = i / IN_CH, c = i % IN_CH;
        s_lw[c][o] = lw[i];
        s_rw[c][o] = rw[i];
    }
    if (threadIdx.x < HID) s_lb[threadIdx.x] = lb[threadIdx.x];

    int sub = threadIdx.x >> 6, lane = threadIdx.x & 63;
    int j = lane >> 4, c = lane & 15;
    int groups = (N + 3) >> 2;
    for (int g = blockIdx.x; g < groups; g += gridDim.x) {
        int n = g * 4 + sub;
        bool valid = n < N;
        int beg = 0, end = 0;
        if (valid) { beg = off_dst[n]; end = off_dst[n + 1]; }
        float a0 = 0.f, a1 = 0.f, a2 = 0.f, a3 = 0.f;
        int i = beg;
        if (valid && c < IN_CH) {
            for (; i + 15 < end; i += 16) {
                int s0 = srcid[i + j];
                int s1 = srcid[i + j + 4];
                int s2 = srcid[i + j + 8];
                int s3 = srcid[i + j + 12];
                a0 += x0[(long)s0 * IN_CH + c];
                a1 += x0[(long)s1 * IN_CH + c];
                a2 += x0[(long)s2 * IN_CH + c];
                a3 += x0[(long)s3 * IN_CH + c];
            }
            for (; i + j < end; i += 4) a0 += x0[(long)srcid[i + j] * IN_CH + c];
        }
        float acc = (a0 + a1) + (a2 + a3);
        acc += __shfl_xor(acc, 16, 64);
        acc += __shfl_xor(acc, 32, 64);
        if (valid && lane < IN_CH) {
            float inv = 1.0f / fmaxf((float)(end - beg), 1.0f);
            s_mean[sub][lane] = acc * inv;
            s_hin[sub][lane] = x0[(long)n * IN_CH + lane];
        }
        __syncthreads();
        if (valid) {
            float oacc = s_lb[lane];
#pragma unroll
            for (int cc = 0; cc < IN_CH; ++cc)
                oacc += s_mean[sub][cc] * s_lw[cc][lane] + s_hin[sub][cc] * s_rw[cc][lane];
            h_out[(long)n * HID + lane] = fmaxf(oacc, 0.0f);
        }
        __syncthreads();
    }
}

// ---------------------------------------------------------------------------
// layer_hid_fused: mean-agg over h (64 ch, lane=channel, 8-deep unroll) +
// relu(mean@lw.T + lb + h@rw.T). Persistent grid; 34 KB LDS (4 blocks/CU).
// ---------------------------------------------------------------------------
__global__ void layer_hid_fused(const float* __restrict__ h_in,
                                const int* __restrict__ off_dst,
                                const int* __restrict__ srcid,
                                const float* __restrict__ lw,
                                const float* __restrict__ lb,
                                const float* __restrict__ rw,
                                float* __restrict__ h_out, int N) {
    __shared__ float s_lw[HID][HID];    // 16 KB, transposed [c][o]
    __shared__ float s_rw[HID][HID];    // 16 KB
    __shared__ float s_lb[HID];
    __shared__ float s_mean[4][HID];
    __shared__ float s_hin[4][HID];
    for (int i = threadIdx.x; i < HID * HID; i += 256) {
        int o = i >> 6, c = i & 63;
        s_lw[c][o] = lw[i];
        s_rw[c][o] = rw[i];
    }
    if (threadIdx.x < HID) s_lb[threadIdx.x] = lb[threadIdx.x];

    int sub = threadIdx.x >> 6, lane = threadIdx.x & 63;
    int groups = (N + 3) >> 2;
    for (int g = blockIdx.x; g < groups; g += gridDim.x) {
        int n = g * 4 + sub;
        bool valid = n < N;
        int beg = 0, end = 0;
        if (valid) { beg = off_dst[n]; end = off_dst[n + 1]; }
        float a0 = 0.f, a1 = 0.f, a2 = 0.f, a3 = 0.f;
        float a4 = 0.f, a5 = 0.f, a6 = 0.f, a7 = 0.f;
        int i = beg;
        for (; i + 7 < end; i += 8) {
            int s0 = srcid[i], s1 = srcid[i + 1], s2 = srcid[i + 2], s3 = srcid[i + 3];
            int s4 = srcid[i + 4], s5 = srcid[i + 5], s6 = srcid[i + 6], s7 = srcid[i + 7];
            a0 += h_in[(long)s0 * HID + lane];
            a1 += h_in[(long)s1 * HID + lane];
            a2 += h_in[(long)s2 * HID + lane];
            a3 += h_in[(long)s3 * HID + lane];
            a4 += h_in[(long)s4 * HID + lane];
            a5 += h_in[(long)s5 * HID + lane];
            a6 += h_in[(long)s6 * HID + lane];
            a7 += h_in[(long)s7 * HID + lane];
        }
        for (; i < end; ++i) a0 += h_in[(long)srcid[i] * HID + lane];
        if (valid) {
            float inv = 1.0f / fmaxf((float)(end - beg), 1.0f);
            s_mean[sub][lane] = (((a0 + a1) + (a2 + a3)) + ((a4 + a5) + (a6 + a7))) * inv;
            s_hin[sub][lane] = h_in[(long)n * HID + lane];
        }
        __syncthreads();
        if (valid) {
            float oacc = s_lb[lane];
#pragma unroll
            for (int cc = 0; cc < HID; ++cc)
                oacc += s_mean[sub][cc] * s_lw[cc][lane] + s_hin[sub][cc] * s_rw[cc][lane];
            h_out[(long)n * HID + lane] = fmaxf(oacc, 0.0f);
        }
        __syncthreads();
    }
}

// ---------------------------------------------------------------------------
// Pooling over sorted batch
// ---------------------------------------------------------------------------
__global__ void pool_kernel(const float* __restrict__ h,
                            const int* __restrict__ batch,
                            float* __restrict__ psum,
                            float* __restrict__ pcnt,
                            int N, int chunk) {
    int lane = threadIdx.x;  // 64
    int n0 = blockIdx.x * chunk;
    int n1 = min(n0 + chunk, N);
    float acc = 0.0f, cnt = 0.0f;
    int cur = -1;
    for (int n = n0; n < n1; ++n) {
        int g = batch[n];
        if (g != cur) {
            if (cur >= 0) {
                atomicAdd(&psum[(long)cur * HID + lane], acc);
                if (lane == 0) atomicAdd(&pcnt[cur], cnt);
            }
            cur = g;
            acc = 0.0f;
            cnt = 0.0f;
        }
        acc += h[(long)n * HID + lane];
        cnt += 1.0f;
    }
    if (cur >= 0) {
        atomicAdd(&psum[(long)cur * HID + lane], acc);
        if (lane == 0) atomicAdd(&pcnt[cur], cnt);
    }
}

__global__ void final_kernel(const float* __restrict__ psum,
                             const float* __restrict__ pcnt,
                             const float* __restrict__ wf,
                             const float* __restrict__ bf,
                             float* __restrict__ out, int G) {
    int g = blockIdx.x * blockDim.x + threadIdx.x;
    if (g < G) {
        float inv = 1.0f / fmaxf(pcnt[g], 1.0f);
        float o0 = bf[0], o1 = bf[1];
#pragma unroll
        for (int c = 0; c < HID; ++c) {
            float p = psum[(long)g * HID + c] * inv;
            o0 += p * wf[c];
            o1 += p * wf[HID + c];
        }
        out[g * N_CLS + 0] = o0;
        out[g * N_CLS + 1] = o1;
    }
}

extern "C" void kernel_launch(void* const* d_in, const int* in_sizes, int n_in,
                              void* d_out, int out_size, void* d_ws, size_t ws_size,
                              hipStream_t stream) {
    const float* x         = (const float*)d_in[0];
    const float* edge_attr = (const float*)d_in[1];
    const int*   edge_idx  = (const int*)d_in[2];
    const int*   batch     = (const int*)d_in[3];
    const float* we  = (const float*)d_in[4];
    const float* be  = (const float*)d_in[5];
    const float* l1w = (const float*)d_in[6];
    const float* l1b = (const float*)d_in[7];
    const float* r1w = (const float*)d_in[8];
    const float* l2w = (const float*)d_in[9];
    const float* l2b = (const float*)d_in[10];
    const float* r2w = (const float*)d_in[11];
    const float* l3w = (const float*)d_in[12];
    const float* l3b = (const float*)d_in[13];
    const float* r3w = (const float*)d_in[14];
    const float* wf  = (const float*)d_in[15];
    const float* bf  = (const float*)d_in[16];

    const int E = in_sizes[2] / 2;
    const int N = in_sizes[3];
    const int* src = edge_idx;
    const int* dst = edge_idx + E;
    const int nbuk = (N + BK_NODES - 1) >> BK_SHIFT;   // 391

    // ---- workspace layout ----
    char* p = (char*)d_ws;
    int* off_dst   = (int*)p;            p += (size_t)(N + 1) * 4;
    int* bc_src    = (int*)p;            p += (size_t)MAXBUK * 4;
    int* bc_dst    = (int*)p;            p += (size_t)MAXBUK * 4;
    int* boff_src  = (int*)p;            p += (size_t)(MAXBUK + 1) * 4;
    int* boff_dst  = (int*)p;            p += (size_t)(MAXBUK + 1) * 4;
    int* gcur_src  = (int*)p;            p += (size_t)MAXBUK * 4;
    int* gcur_dst  = (int*)p;            p += (size_t)MAXBUK * 4;
    int* dst_srcid = (int*)p;            p += (size_t)E * 4;
    float* x0      = (float*)p;          p += (size_t)N * IN_CH * 4;
    float* bufA    = (float*)p;          p += (size_t)N * HID * 4;
    float* bufB    = (float*)p;          p += (size_t)N * HID * 4;
    float* psum    = (float*)p;          p += (size_t)N_GRAPHS * HID * 4;
    float* pcnt    = (float*)p;          p += (size_t)N_GRAPHS * 4;

    // bins alias bufB (dead until layer2 writes it; 2*E ints == N*HID floats)
    uint32_t* bin_src = (uint32_t*)bufB;
    uint32_t* bin_dst = bin_src + E;

    // ---- CSR build (LDS-staged counting sort) ----
    hipMemsetAsync(bc_src, 0, (size_t)MAXBUK * 2 * 4, stream);
    prehist_kernel<<<512, 256, 0, stream>>>(src, dst, bc_src, bc_dst, E, nbuk);
    bucket_scan_kernel<<<1, MAXBUK, 0, stream>>>(bc_src, bc_dst, boff_src, boff_dst,
                                                 gcur_src, gcur_dst, off_dst,
                                                 nbuk, N, E);
    binscatter_kernel<<<(E + L1_CHUNK - 1) / L1_CHUNK, 512, 0, stream>>>(
        src, dst, gcur_src, gcur_dst, bin_src, bin_dst, E, nbuk);
    bucket_csr_kernel<<<nbuk, 256, 0, stream>>>(
        bin_dst, boff_dst, dst_srcid, off_dst, nbuk, N);

    // ---- edge correction (fused: segment-sum in LDS + GEMV + outdeg*be) ----
    bucket_ea_kernel<<<nbuk, 256, 0, stream>>>(
        bin_src, boff_src, edge_attr, x, we, be, x0, nbuk, N);

    // ---- layer 1 (fused agg11 + update) ----
    layer1_fused<<<2048, 256, 0, stream>>>(x0, off_dst, dst_srcid, l1w, l1b, r1w, bufA, N);

    // ---- layer 2 (fused agg64 + update); writes bufB, clobbering dead bins ----
    layer_hid_fused<<<1024, 256, 0, stream>>>(bufA, off_dst, dst_srcid, l2w, l2b, r2w, bufB, N);

    // ---- layer 3 ----
    layer_hid_fused<<<1024, 256, 0, stream>>>(bufB, off_dst, dst_srcid, l3w, l3b, r3w, bufA, N);

    // ---- pool + classify ----
    hipMemsetAsync(psum, 0, (size_t)(N_GRAPHS * HID + N_GRAPHS) * 4, stream);
    {
        int pb = 1024;
        int chunk = (N + pb - 1) / pb;
        pool_kernel<<<pb, 64, 0, stream>>>(bufA, batch, psum, pcnt, N, chunk);
    }
    final_kernel<<<(N_GRAPHS + 255) / 256, 256, 0, stream>>>(psum, pcnt, wf, bf,
                                                             (float*)d_out, N_GRAPHS);
}